// Round 3
// baseline (319.737 us; speedup 1.0000x reference)
//
#include <hip/hip_runtime.h>
#include <math.h>

#define HP 258
#define NPIX (HP*HP)          // 66564
#define C30 30
#define TOT (C30*NPIX)        // 1996920
#define LOGW 64
#define LDSK 40               // LDS k-stride (bf16 elems)

typedef __bf16 bf16x8 __attribute__((ext_vector_type(8)));
typedef float  f32x4  __attribute__((ext_vector_type(4)));
typedef unsigned short ushort;
typedef unsigned short ushort8 __attribute__((ext_vector_type(8)));

static __device__ inline ushort f2bf(float f){
  __bf16 h = (__bf16)f;
  return __builtin_bit_cast(ushort, h);
}

// ---------------- build padded fc channels (30 distinct, each x2 in ref) ----
__global__ void build_fc_k(const float* __restrict__ logits,
                           float* __restrict__ xp, ushort* __restrict__ xpbf){
  int p = blockIdx.x*256 + threadIdx.x;
  if (p >= NPIX) return;
  int h = p / HP, w = p % HP;
  if (h==0 || h==HP-1 || w==0 || w==HP-1){
    ushort one = f2bf(1.0f);
    #pragma unroll
    for (int c=0;c<C30;c++){ xp[c*NPIX+p] = 1.0f; xpbf[c*NPIX+p] = one; }
    return;
  }
  int oh = h-1, ow = w-1;
  float fy = 0.25f*oh - 0.375f;
  float fx = 0.25f*ow - 0.375f;
  float y0f = floorf(fy), x0f = floorf(fx);
  float ty = fy - y0f, tx = fx - x0f;
  int y0 = max(0, (int)y0f), y1 = min(LOGW-1, (int)y0f + 1);
  int x0 = max(0, (int)x0f), x1 = min(LOGW-1, (int)x0f + 1);
  float s[6];
  float m = -3.402823466e+38f;
  #pragma unroll
  for (int c=0;c<6;c++){
    const float* pl = logits + c*LOGW*LOGW;
    float v00 = pl[y0*LOGW + x0], v01 = pl[y0*LOGW + x1];
    float v10 = pl[y1*LOGW + x0], v11 = pl[y1*LOGW + x1];
    float a = v00 + (v01 - v00)*tx;
    float b = v10 + (v11 - v10)*tx;
    float v = a + (b - a)*ty;
    s[c] = v; m = fmaxf(m, v);
  }
  float sum = 0.0f;
  #pragma unroll
  for (int c=0;c<6;c++){ s[c] = expf(s[c]-m); sum += s[c]; }
  float inv = 1.0f/sum;
  #pragma unroll
  for (int c=0;c<6;c++) s[c] *= inv;
  #pragma unroll
  for (int c=0;c<C30;c++){
    int i = c/5, r = c%5;
    int j = r + (r>=i ? 1 : 0);
    float d = 0.5f*(s[i]-s[j]);
    float v = fmaxf(d, 0.0f);
    xp[c*NPIX+p]  = v;
    xpbf[c*NPIX+p] = f2bf(v);
  }
}

// ---------------- transpose bf16 per channel: dst[n*HP+k] = src[k*HP+n] ----
__global__ void transpose_k(const ushort* __restrict__ src, ushort* __restrict__ dst){
  __shared__ ushort t[32][33];
  int ch = blockIdx.z;
  const ushort* s = src + (size_t)ch*NPIX;
  ushort*       d = dst + (size_t)ch*NPIX;
  int c0 = blockIdx.x*32, r0 = blockIdx.y*32;
  #pragma unroll
  for (int i=0;i<4;i++){
    int r = r0 + threadIdx.y + i*8, c = c0 + threadIdx.x;
    t[threadIdx.y+i*8][threadIdx.x] = (r<HP && c<HP) ? s[r*HP+c] : (ushort)0;
  }
  __syncthreads();
  #pragma unroll
  for (int i=0;i<4;i++){
    int r = r0 + threadIdx.x, c = c0 + threadIdx.y + i*8;
    if (c<HP && r<HP) d[(size_t)c*HP + r] = t[threadIdx.x][threadIdx.y+i*8];
  }
}

// ---------------- fused pool(A) MFMA matmul: C = poolpad(X) @ B ------------
// MAXP=1: maxpool, MAXP=0: avgpool. B from pre-transposed bf16 (XPbfT).
template<int MAXP>
__global__ __launch_bounds__(256) void mm_pool_k(const float* __restrict__ X,
                                                 const ushort* __restrict__ BT,
                                                 float* __restrict__ C){
  __shared__ ushort As[64*LDSK];
  __shared__ ushort Bs[64*LDSK];
  int ch = blockIdx.z;
  const float*  Xb = X  + (size_t)ch*NPIX;
  const ushort* Bb = BT + (size_t)ch*NPIX;
  float*        Cb = C  + (size_t)ch*NPIX;
  int tid = threadIdx.x;
  int lane = tid & 63, wv = tid >> 6;
  int wr = (wv >> 1)*32, wc = (wv & 1)*32;
  int rowBase = blockIdx.x*64, colBase = blockIdx.y*64;
  int l15 = lane & 15, lq = lane >> 4;

  f32x4 acc00 = {0.f,0.f,0.f,0.f}, acc01 = acc00, acc10 = acc00, acc11 = acc00;

  int arow = tid >> 2, akb = (tid & 3)*8;
  int bn   = tid & 63, bkb = (tid >> 6)*8;
  int agr = rowBase + arow;
  int bgc = colBase + bn;

  for (int k0 = 0; k0 < HP; k0 += 32){
    // ---- stage A: pooled+padded X -> bf16 ----
    {
      int gk0 = k0 + akb;
      ushort8 t8;
      if (agr >= HP){
        #pragma unroll
        for (int i=0;i<8;i++) t8[i] = 0;
      } else if (agr == 0 || agr == HP-1){
        ushort one = f2bf(1.0f);
        #pragma unroll
        for (int i=0;i<8;i++) t8[i] = (gk0+i < HP) ? one : (ushort)0;
      } else {
        float colv[10];
        int klo = max(1, gk0), khi = min(HP-2, gk0+7);
        if (klo <= khi){
          const float* r0 = Xb + (size_t)(agr-1)*HP;
          const float* r1 = Xb + (size_t)agr*HP;
          const float* r2 = Xb + (size_t)(agr+1)*HP;
          for (int c = klo-1; c <= khi+1; c++){
            float a = r0[c], b = r1[c], d = r2[c];
            colv[c-(gk0-1)] = MAXP ? fmaxf(fmaxf(a,b),d) : (a+b+d);
          }
        }
        #pragma unroll
        for (int i=0;i<8;i++){
          int k = gk0 + i;
          float v;
          if (k >= HP) v = 0.0f;
          else if (k == 0 || k == HP-1) v = 1.0f;
          else {
            float p0 = colv[i], p1 = colv[i+1], p2 = colv[i+2];
            v = MAXP ? fmaxf(fmaxf(p0,p1),p2) : (p0+p1+p2)*(1.0f/9.0f);
          }
          t8[i] = f2bf(v);
        }
      }
      *(ushort8*)(&As[arow*LDSK + akb]) = t8;
    }
    // ---- stage B: contiguous from transposed bf16 ----
    {
      ushort8 t8;
      if (bgc < HP && k0 + bkb + 8 <= HP){
        t8 = *(const ushort8*)(Bb + (size_t)bgc*HP + k0 + bkb);
      } else {
        #pragma unroll
        for (int i=0;i<8;i++){
          int kk = k0 + bkb + i;
          t8[i] = (bgc < HP && kk < HP) ? Bb[(size_t)bgc*HP + kk] : (ushort)0;
        }
      }
      *(ushort8*)(&Bs[bn*LDSK + bkb]) = t8;
    }
    __syncthreads();
    bf16x8 a0 = __builtin_bit_cast(bf16x8, *(const ushort8*)(&As[(wr      + l15)*LDSK + lq*8]));
    bf16x8 a1 = __builtin_bit_cast(bf16x8, *(const ushort8*)(&As[(wr + 16 + l15)*LDSK + lq*8]));
    bf16x8 b0 = __builtin_bit_cast(bf16x8, *(const ushort8*)(&Bs[(wc      + l15)*LDSK + lq*8]));
    bf16x8 b1 = __builtin_bit_cast(bf16x8, *(const ushort8*)(&Bs[(wc + 16 + l15)*LDSK + lq*8]));
    acc00 = __builtin_amdgcn_mfma_f32_16x16x32_bf16(a0, b0, acc00, 0, 0, 0);
    acc01 = __builtin_amdgcn_mfma_f32_16x16x32_bf16(a0, b1, acc01, 0, 0, 0);
    acc10 = __builtin_amdgcn_mfma_f32_16x16x32_bf16(a1, b0, acc10, 0, 0, 0);
    acc11 = __builtin_amdgcn_mfma_f32_16x16x32_bf16(a1, b1, acc11, 0, 0, 0);
    __syncthreads();
  }
  auto store = [&](f32x4 v, int r0, int c0){
    if (c0 < HP){
      #pragma unroll
      for (int r=0;r<4;r++){
        int rr = r0 + r;
        if (rr < HP) Cb[(size_t)rr*HP + c0] = v[r];
      }
    }
  };
  store(acc00, rowBase + wr +      lq*4, colBase + wc +      l15);
  store(acc01, rowBase + wr +      lq*4, colBase + wc + 16 + l15);
  store(acc10, rowBase + wr + 16 + lq*4, colBase + wc +      l15);
  store(acc11, rowBase + wr + 16 + lq*4, colBase + wc + 16 + l15);
}

// ---- fused final matmul: C = (X*invn) @ (±B); reduce |operand - C| --------
// NEGB=1: B = border?1:-XPbf, operand = border?1:-XP (opening)
// NEGB=0: B = XPbf,           operand = XP           (dilation)
template<int NEGB>
__global__ __launch_bounds__(256) void mm_norm_abs_k(const float* __restrict__ X,
                                                     const float* __restrict__ invn,
                                                     const ushort* __restrict__ BT,
                                                     const float* __restrict__ XPop,
                                                     double* __restrict__ part){
  __shared__ ushort As[64*LDSK];
  __shared__ ushort Bs[64*LDSK];
  __shared__ double red[256];
  int ch = blockIdx.z;
  const float*  Xb = X   + (size_t)ch*NPIX;
  const ushort* Bb = BT  + (size_t)ch*NPIX;
  const float*  Ob = XPop+ (size_t)ch*NPIX;
  int tid = threadIdx.x;
  int lane = tid & 63, wv = tid >> 6;
  int wr = (wv >> 1)*32, wc = (wv & 1)*32;
  int rowBase = blockIdx.x*64, colBase = blockIdx.y*64;
  int l15 = lane & 15, lq = lane >> 4;

  f32x4 acc00 = {0.f,0.f,0.f,0.f}, acc01 = acc00, acc10 = acc00, acc11 = acc00;

  int arow = tid >> 2, akb = (tid & 3)*8;
  int bn   = tid & 63, bkb = (tid >> 6)*8;
  int agr = rowBase + arow;
  int bgc = colBase + bn;

  for (int k0 = 0; k0 < HP; k0 += 32){
    // ---- stage A: X * invn -> bf16 ----
    {
      int gk = k0 + akb;
      ushort8 t8;
      if (agr < HP && gk + 8 <= HP){
        const float* p = Xb + (size_t)agr*HP + gk;
        const float* q = invn + (size_t)agr*HP + gk;
        #pragma unroll
        for (int i=0;i<8;i+=2){
          float2 f = *(const float2*)(p+i);
          float2 g = *(const float2*)(q+i);
          t8[i]   = f2bf(f.x*g.x);
          t8[i+1] = f2bf(f.y*g.y);
        }
      } else {
        #pragma unroll
        for (int i=0;i<8;i++){
          int kk = gk + i;
          float v = (agr < HP && kk < HP) ? Xb[(size_t)agr*HP + kk]*invn[(size_t)agr*HP + kk] : 0.0f;
          t8[i] = f2bf(v);
        }
      }
      *(ushort8*)(&As[arow*LDSK + akb]) = t8;
    }
    // ---- stage B (optionally negated except borders) ----
    {
      ushort8 t8;
      int kb0 = k0 + bkb;
      if (bgc < HP && kb0 + 8 <= HP){
        t8 = *(const ushort8*)(Bb + (size_t)bgc*HP + kb0);
        if (NEGB){
          if (bgc == 0 || bgc == HP-1){
            ushort one = f2bf(1.0f);
            #pragma unroll
            for (int i=0;i<8;i++) t8[i] = one;
          } else {
            #pragma unroll
            for (int i=0;i<8;i++){
              int kk = kb0 + i;
              t8[i] = (kk==0 || kk==HP-1) ? f2bf(1.0f) : (ushort)(t8[i] ^ 0x8000);
            }
          }
        }
      } else {
        #pragma unroll
        for (int i=0;i<8;i++){
          int kk = kb0 + i;
          ushort v = (bgc < HP && kk < HP) ? Bb[(size_t)bgc*HP + kk] : (ushort)0;
          if (NEGB && bgc < HP && kk < HP){
            v = (bgc==0||bgc==HP-1||kk==0||kk==HP-1) ? f2bf(1.0f) : (ushort)(v ^ 0x8000);
          }
          t8[i] = v;
        }
      }
      *(ushort8*)(&Bs[bn*LDSK + bkb]) = t8;
    }
    __syncthreads();
    bf16x8 a0 = __builtin_bit_cast(bf16x8, *(const ushort8*)(&As[(wr      + l15)*LDSK + lq*8]));
    bf16x8 a1 = __builtin_bit_cast(bf16x8, *(const ushort8*)(&As[(wr + 16 + l15)*LDSK + lq*8]));
    bf16x8 b0 = __builtin_bit_cast(bf16x8, *(const ushort8*)(&Bs[(wc      + l15)*LDSK + lq*8]));
    bf16x8 b1 = __builtin_bit_cast(bf16x8, *(const ushort8*)(&Bs[(wc + 16 + l15)*LDSK + lq*8]));
    acc00 = __builtin_amdgcn_mfma_f32_16x16x32_bf16(a0, b0, acc00, 0, 0, 0);
    acc01 = __builtin_amdgcn_mfma_f32_16x16x32_bf16(a0, b1, acc01, 0, 0, 0);
    acc10 = __builtin_amdgcn_mfma_f32_16x16x32_bf16(a1, b0, acc10, 0, 0, 0);
    acc11 = __builtin_amdgcn_mfma_f32_16x16x32_bf16(a1, b1, acc11, 0, 0, 0);
    __syncthreads();
  }
  // epilogue: sum |operand - acc| (no C write)
  double local = 0.0;
  auto addq = [&](f32x4 v, int r0, int c0){
    if (c0 < HP){
      #pragma unroll
      for (int r=0;r<4;r++){
        int rr = r0 + r;
        if (rr < HP){
          float o = Ob[(size_t)rr*HP + c0];
          if (NEGB) o = (rr==0||rr==HP-1||c0==0||c0==HP-1) ? 1.0f : -o;
          local += (double)fabsf(o - v[r]);
        }
      }
    }
  };
  addq(acc00, rowBase + wr +      lq*4, colBase + wc +      l15);
  addq(acc01, rowBase + wr +      lq*4, colBase + wc + 16 + l15);
  addq(acc10, rowBase + wr + 16 + lq*4, colBase + wc +      l15);
  addq(acc11, rowBase + wr + 16 + lq*4, colBase + wc + 16 + l15);
  red[tid] = local;
  __syncthreads();
  for (int s=128; s>0; s>>=1){ if (tid<s) red[tid]+=red[tid+s]; __syncthreads(); }
  if (tid==0) part[(size_t)blockIdx.z*25 + blockIdx.y*5 + blockIdx.x] = red[0];
}

// ---------------- column-sum partials of (y - x) over row chunks ------------
__global__ void colmean_part_k(const float* __restrict__ y, const float* __restrict__ x,
                               float* __restrict__ cmpart){
  int c = blockIdx.z, chunk = blockIdx.y;
  int w = blockIdx.x*256 + threadIdx.x;
  if (w >= HP) return;
  const float* yb = y + (size_t)c*NPIX;
  const float* xb = x + (size_t)c*NPIX;
  int r0 = chunk*33, r1 = min(HP, r0+33);
  float sum = 0.0f;
  for (int h=r0; h<r1; h++) sum += yb[h*HP+w] - xb[h*HP+w];
  cmpart[((size_t)chunk*C30 + c)*HP + w] = sum;
}

__global__ void combine_cm_k(const float* __restrict__ cmpart, float* __restrict__ cm){
  int idx = blockIdx.x*256 + threadIdx.x;
  if (idx >= C30*HP) return;
  float s = 0.0f;
  #pragma unroll
  for (int k=0;k<8;k++) s += cmpart[(size_t)k*C30*HP + idx];
  cm[idx] = s / (float)HP;
}

// ---------------- rectification: out = x + relu((y-x) - colmean) ------------
__global__ void rectify_k(const float* __restrict__ x, const float* __restrict__ y,
                          const float* __restrict__ cm, float* __restrict__ out){
  int idx = blockIdx.x*256 + threadIdx.x;
  if (idx >= TOT) return;
  int c = idx / NPIX, p = idx % NPIX;
  int w = p % HP;
  float xv = x[idx];
  float off = y[idx] - xv - cm[c*HP + w];
  out[idx] = xv + fmaxf(off, 0.0f);
}

// ------------- fused rectify + per-pixel inv-norm (over 30 ch, x2) ----------
__global__ void rectify_invnorm_k(const float* __restrict__ x, const float* __restrict__ y,
                                  const float* __restrict__ cm, float* __restrict__ out,
                                  float* __restrict__ invn){
  int p = blockIdx.x*256 + threadIdx.x;
  if (p >= NPIX) return;
  int w = p % HP;
  float ss = 0.0f;
  #pragma unroll
  for (int c=0;c<C30;c++){
    float xv = x[(size_t)c*NPIX + p];
    float off = y[(size_t)c*NPIX + p] - xv - cm[c*HP + w];
    float v = xv + fmaxf(off, 0.0f);
    out[(size_t)c*NPIX + p] = v;
    ss = fmaf(v, v, ss);
  }
  float n = sqrtf(2.0f*ss);
  invn[p] = 1.0f / fmaxf(n, 1e-12f);
}

// ---------------- per-pixel inv-norm over 30 channels (x2 dup) --------------
__global__ void invnorm_k(const float* __restrict__ oper, float* __restrict__ invn){
  int p = blockIdx.x*256 + threadIdx.x;
  if (p >= NPIX) return;
  float ss = 0.0f;
  #pragma unroll
  for (int c=0;c<C30;c++){ float v = oper[(size_t)c*NPIX+p]; ss = fmaf(v,v,ss); }
  float n = sqrtf(2.0f*ss);
  invn[p] = 1.0f / fmaxf(n, 1e-12f);
}

// ---------------- final: |2*(S0 - S1)| + base_loss --------------------------
__global__ void finalize_k(const double* __restrict__ part,
                           const float* __restrict__ base, float* __restrict__ out){
  __shared__ double s0[256], s1[256];
  int tid = threadIdx.x;
  double l0=0.0, l1=0.0;
  for (int i=tid;i<750;i+=256){ l0 += part[i]; l1 += part[750+i]; }
  s0[tid]=l0; s1[tid]=l1; __syncthreads();
  for (int s=128;s>0;s>>=1){ if (tid<s){ s0[tid]+=s0[tid+s]; s1[tid]+=s1[tid+s]; } __syncthreads(); }
  if (tid==0){
    out[0] = (float)(fabs(2.0*(s0[0]-s1[0])) + (double)base[0]);
  }
}

extern "C" void kernel_launch(void* const* d_in, const int* in_sizes, int n_in,
                              void* d_out, int out_size, void* d_ws, size_t ws_size,
                              hipStream_t stream){
  const float* logits = (const float*)d_in[0];
  const float* base   = (const float*)d_in[1];
  float* out = (float*)d_out;

  char* ws = (char*)d_ws;
  size_t off = 0;
  auto alloc = [&](size_t bytes)->char*{
    char* p = ws + off; off = (off + bytes + 255) & ~(size_t)255; return p;
  };
  double* part   = (double*)alloc(1500*sizeof(double));
  float*  cm     = (float*) alloc((size_t)C30*HP*sizeof(float));
  float*  cmpart = (float*) alloc((size_t)8*C30*HP*sizeof(float));
  float*  invn   = (float*) alloc((size_t)NPIX*sizeof(float));
  float*  XP     = (float*) alloc((size_t)TOT*sizeof(float));
  ushort* XPbf   = (ushort*)alloc((size_t)TOT*sizeof(ushort));
  ushort* XPbfT  = (ushort*)alloc((size_t)TOT*sizeof(ushort));
  float*  Abuf   = (float*) alloc((size_t)TOT*sizeof(float));
  float*  Bbuf   = (float*) alloc((size_t)TOT*sizeof(float));
  float*  Cbuf   = (float*) alloc((size_t)TOT*sizeof(float));
  (void)ws_size; (void)in_sizes; (void)n_in; (void)out_size;

  dim3 mmGrid((HP+63)/64, (HP+63)/64, C30);          // 5 x 5 x 30
  dim3 trGrid((HP+31)/32, (HP+31)/32, C30);          // 9 x 9 x 30
  dim3 cmGrid((HP+255)/256, 8, C30);                 // 2 x 8 x 30
  int eb = (NPIX+255)/256;
  int tb = (TOT+255)/256;
  int cb = (C30*HP+255)/256;

  build_fc_k<<<eb,256,0,stream>>>(logits, XP, XPbf);
  transpose_k<<<trGrid,dim3(32,8),0,stream>>>(XPbf, XPbfT);

  // ---- opening: x = maxpoolpad(x) @ XP (x2); |OPN - norm@OPN| ----
  mm_pool_k<1><<<mmGrid,256,0,stream>>>(XP, XPbfT, Bbuf);
  mm_pool_k<1><<<mmGrid,256,0,stream>>>(Bbuf, XPbfT, Cbuf);      // operated_open
  invnorm_k<<<eb,256,0,stream>>>(Cbuf, invn);
  mm_norm_abs_k<1><<<mmGrid,256,0,stream>>>(Cbuf, invn, XPbfT, XP, part);

  // ---- dilation ----
  mm_pool_k<0><<<mmGrid,256,0,stream>>>(XP, XPbfT, Bbuf);        // y1
  colmean_part_k<<<cmGrid,256,0,stream>>>(Bbuf, XP, cmpart);
  combine_cm_k<<<cb,256,0,stream>>>(cmpart, cm);
  rectify_k<<<tb,256,0,stream>>>(XP, Bbuf, cm, Cbuf);            // x1
  mm_pool_k<0><<<mmGrid,256,0,stream>>>(Cbuf, XPbfT, Abuf);      // y2
  colmean_part_k<<<cmGrid,256,0,stream>>>(Abuf, Cbuf, cmpart);
  combine_cm_k<<<cb,256,0,stream>>>(cmpart, cm);
  rectify_invnorm_k<<<eb,256,0,stream>>>(Cbuf, Abuf, cm, Bbuf, invn); // x2
  mm_norm_abs_k<0><<<mmGrid,256,0,stream>>>(Bbuf, invn, XPbfT, XP, part + 750);

  finalize_k<<<1,256,0,stream>>>(part, base, out);
}

// Round 4
// 184.407 us; speedup vs baseline: 1.7339x; 1.7339x over previous
//
#include <hip/hip_runtime.h>
#include <math.h>

#define HP 258
#define BSTR 264              // bf16 row stride (528B, 16B-aligned)
#define NPIX (HP*HP)          // 66564
#define NPB  (HP*BSTR)        // 68112 bf16 elems per channel
#define C30 30
#define TOT (C30*NPIX)
#define LOGW 64
#define LDSK 40               // LDS k-stride (bf16 elems)

typedef __bf16 bf16x8 __attribute__((ext_vector_type(8)));
typedef float  f32x4  __attribute__((ext_vector_type(4)));
typedef unsigned short ushort;
typedef unsigned short ushort8 __attribute__((ext_vector_type(8)));

static __device__ inline ushort f2bf(float f){
  __bf16 h = (__bf16)f;
  return __builtin_bit_cast(ushort, h);
}

// ---------------- build padded fc channels (30 distinct, each x2 in ref) ----
__global__ void build_fc_k(const float* __restrict__ logits,
                           float* __restrict__ xp, ushort* __restrict__ xpbf){
  int p = blockIdx.x*256 + threadIdx.x;
  if (p >= NPIX) return;
  int h = p / HP, w = p % HP;
  size_t pb = (size_t)h*BSTR + w;
  if (h==0 || h==HP-1 || w==0 || w==HP-1){
    ushort one = f2bf(1.0f);
    #pragma unroll
    for (int c=0;c<C30;c++){ xp[(size_t)c*NPIX+p] = 1.0f; xpbf[(size_t)c*NPB+pb] = one; }
    return;
  }
  int oh = h-1, ow = w-1;
  float fy = 0.25f*oh - 0.375f;
  float fx = 0.25f*ow - 0.375f;
  float y0f = floorf(fy), x0f = floorf(fx);
  float ty = fy - y0f, tx = fx - x0f;
  int y0 = max(0, (int)y0f), y1 = min(LOGW-1, (int)y0f + 1);
  int x0 = max(0, (int)x0f), x1 = min(LOGW-1, (int)x0f + 1);
  float s[6];
  float m = -3.402823466e+38f;
  #pragma unroll
  for (int c=0;c<6;c++){
    const float* pl = logits + c*LOGW*LOGW;
    float v00 = pl[y0*LOGW + x0], v01 = pl[y0*LOGW + x1];
    float v10 = pl[y1*LOGW + x0], v11 = pl[y1*LOGW + x1];
    float a = v00 + (v01 - v00)*tx;
    float b = v10 + (v11 - v10)*tx;
    float v = a + (b - a)*ty;
    s[c] = v; m = fmaxf(m, v);
  }
  float sum = 0.0f;
  #pragma unroll
  for (int c=0;c<6;c++){ s[c] = expf(s[c]-m); sum += s[c]; }
  float inv = 1.0f/sum;
  #pragma unroll
  for (int c=0;c<6;c++) s[c] *= inv;
  #pragma unroll
  for (int c=0;c<C30;c++){
    int i = c/5, r = c%5;
    int j = r + (r>=i ? 1 : 0);
    float d = 0.5f*(s[i]-s[j]);
    float v = fmaxf(d, 0.0f);
    xp[(size_t)c*NPIX+p]  = v;
    xpbf[(size_t)c*NPB+pb] = f2bf(v);
  }
}

// ---------------- transpose bf16 per channel (BSTR stride both sides) ------
__global__ void transpose_k(const ushort* __restrict__ src, ushort* __restrict__ dst){
  __shared__ ushort t[32][33];
  int ch = blockIdx.z;
  const ushort* s = src + (size_t)ch*NPB;
  ushort*       d = dst + (size_t)ch*NPB;
  int c0 = blockIdx.x*32, r0 = blockIdx.y*32;
  #pragma unroll
  for (int i=0;i<4;i++){
    int r = r0 + threadIdx.y + i*8, c = c0 + threadIdx.x;
    t[threadIdx.y+i*8][threadIdx.x] = (r<HP && c<HP) ? s[(size_t)r*BSTR+c] : (ushort)0;
  }
  __syncthreads();
  #pragma unroll
  for (int i=0;i<4;i++){
    int r = r0 + threadIdx.x, c = c0 + threadIdx.y + i*8;
    if (c<HP && r<HP) d[(size_t)c*BSTR + r] = t[threadIdx.x][threadIdx.y+i*8];
  }
}

// ------------- combined max+avg 3x3 pool + pad, fp32 in -> bf16 out ---------
__global__ void pool_both_k(const float* __restrict__ X,
                            ushort* __restrict__ pmax, ushort* __restrict__ pavg){
  int c = blockIdx.y;
  int p = blockIdx.x*256 + threadIdx.x;
  if (p >= NPIX) return;
  int h = p / HP, w = p % HP;
  size_t ob = (size_t)c*NPB + (size_t)h*BSTR + w;
  if (h==0 || h==HP-1 || w==0 || w==HP-1){
    ushort one = f2bf(1.0f);
    pmax[ob] = one; pavg[ob] = one;
    return;
  }
  const float* s = X + (size_t)c*NPIX;
  float mv = -3.402823466e+38f, av = 0.0f;
  #pragma unroll
  for (int dy=-1;dy<=1;dy++){
    const float* r = s + (size_t)(h+dy)*HP + (w-1);
    float a = r[0], b = r[1], d = r[2];
    mv = fmaxf(mv, fmaxf(fmaxf(a,b),d));
    av += a+b+d;
  }
  pmax[ob] = f2bf(mv);
  pavg[ob] = f2bf(av*(1.0f/9.0f));
}

// ---------------- single 3x3 pool + pad, fp32 in -> bf16 out ----------------
template<int MAXP>
__global__ void pool_one_k(const float* __restrict__ X, ushort* __restrict__ out){
  int c = blockIdx.y;
  int p = blockIdx.x*256 + threadIdx.x;
  if (p >= NPIX) return;
  int h = p / HP, w = p % HP;
  size_t ob = (size_t)c*NPB + (size_t)h*BSTR + w;
  if (h==0 || h==HP-1 || w==0 || w==HP-1){ out[ob] = f2bf(1.0f); return; }
  const float* s = X + (size_t)c*NPIX;
  if (MAXP){
    float mv = -3.402823466e+38f;
    #pragma unroll
    for (int dy=-1;dy<=1;dy++){
      const float* r = s + (size_t)(h+dy)*HP + (w-1);
      mv = fmaxf(mv, fmaxf(fmaxf(r[0],r[1]),r[2]));
    }
    out[ob] = f2bf(mv);
  } else {
    float av = 0.0f;
    #pragma unroll
    for (int dy=-1;dy<=1;dy++){
      const float* r = s + (size_t)(h+dy)*HP + (w-1);
      av += r[0]+r[1]+r[2];
    }
    out[ob] = f2bf(av*(1.0f/9.0f));
  }
}

// ---------------- MFMA staging helpers --------------------------------------
#define MM_PROLOGUE()                                                          \
  int tid = threadIdx.x;                                                       \
  int lane = tid & 63, wv = tid >> 6;                                          \
  int wr = (wv >> 1)*32, wc = (wv & 1)*32;                                     \
  int rowBase = blockIdx.x*64, colBase = blockIdx.y*64;                        \
  int l15 = lane & 15, lq = lane >> 4;                                         \
  f32x4 acc00 = {0.f,0.f,0.f,0.f}, acc01 = acc00, acc10 = acc00, acc11 = acc00;\
  int arow = tid >> 2, akb = (tid & 3)*8;                                      \
  int bn   = tid & 63, bkb = (tid >> 6)*8;                                     \
  int agr = rowBase + arow;                                                    \
  int bgc = colBase + bn;

#define MM_MFMA_STEP()                                                         \
  __syncthreads();                                                             \
  {                                                                            \
    bf16x8 a0 = __builtin_bit_cast(bf16x8, *(const ushort8*)(&As[(wr      + l15)*LDSK + lq*8])); \
    bf16x8 a1 = __builtin_bit_cast(bf16x8, *(const ushort8*)(&As[(wr + 16 + l15)*LDSK + lq*8])); \
    bf16x8 b0 = __builtin_bit_cast(bf16x8, *(const ushort8*)(&Bs[(wc      + l15)*LDSK + lq*8])); \
    bf16x8 b1 = __builtin_bit_cast(bf16x8, *(const ushort8*)(&Bs[(wc + 16 + l15)*LDSK + lq*8])); \
    acc00 = __builtin_amdgcn_mfma_f32_16x16x32_bf16(a0, b0, acc00, 0, 0, 0);   \
    acc01 = __builtin_amdgcn_mfma_f32_16x16x32_bf16(a0, b1, acc01, 0, 0, 0);   \
    acc10 = __builtin_amdgcn_mfma_f32_16x16x32_bf16(a1, b0, acc10, 0, 0, 0);   \
    acc11 = __builtin_amdgcn_mfma_f32_16x16x32_bf16(a1, b1, acc11, 0, 0, 0);   \
  }                                                                            \
  __syncthreads();

static __device__ inline ushort8 ldA(const ushort* __restrict__ Ab, int agr, int gk){
  ushort8 t8;
  if (agr < HP && gk + 8 <= HP){
    t8 = *(const ushort8*)(Ab + (size_t)agr*BSTR + gk);
  } else {
    #pragma unroll
    for (int i=0;i<8;i++){
      int kk = gk + i;
      t8[i] = (agr < HP && kk < HP) ? Ab[(size_t)agr*BSTR + kk] : (ushort)0;
    }
  }
  return t8;
}

// ---------------- mm_store: C(fp32) = A(bf16) @ B(bf16 T) -------------------
__global__ __launch_bounds__(256) void mm_store_k(const ushort* __restrict__ A,
                                                  const ushort* __restrict__ BT,
                                                  float* __restrict__ C){
  __shared__ ushort As[64*LDSK];
  __shared__ ushort Bs[64*LDSK];
  int ch = blockIdx.z;
  const ushort* Ab = A  + (size_t)ch*NPB;
  const ushort* Bb = BT + (size_t)ch*NPB;
  float*        Cb = C  + (size_t)ch*NPIX;
  MM_PROLOGUE();
  for (int k0 = 0; k0 < HP; k0 += 32){
    *(ushort8*)(&As[arow*LDSK + akb]) = ldA(Ab, agr, k0 + akb);
    *(ushort8*)(&Bs[bn*LDSK + bkb])   = ldA(Bb, bgc, k0 + bkb);
    MM_MFMA_STEP();
  }
  auto store = [&](f32x4 v, int r0, int c0){
    if (c0 < HP){
      #pragma unroll
      for (int r=0;r<4;r++){
        int rr = r0 + r;
        if (rr < HP) Cb[(size_t)rr*HP + c0] = v[r];
      }
    }
  };
  store(acc00, rowBase + wr +      lq*4, colBase + wc +      l15);
  store(acc01, rowBase + wr +      lq*4, colBase + wc + 16 + l15);
  store(acc10, rowBase + wr + 16 + lq*4, colBase + wc +      l15);
  store(acc11, rowBase + wr + 16 + lq*4, colBase + wc + 16 + l15);
}

// ------- mm_absred: acc = A @ (±B); part += |operand - acc| (no C write) ----
// NEGB=1 (opening): B/operand = border?1:-XP ; NEGB=0 (dilation): B/op = XP
template<int NEGB>
__global__ __launch_bounds__(256) void mm_absred_k(const ushort* __restrict__ A,
                                                   const ushort* __restrict__ BT,
                                                   const float* __restrict__ XPop,
                                                   double* __restrict__ part){
  __shared__ ushort As[64*LDSK];
  __shared__ ushort Bs[64*LDSK];
  __shared__ double red[256];
  int ch = blockIdx.z;
  const ushort* Ab = A   + (size_t)ch*NPB;
  const ushort* Bb = BT  + (size_t)ch*NPB;
  const float*  Ob = XPop+ (size_t)ch*NPIX;
  MM_PROLOGUE();
  for (int k0 = 0; k0 < HP; k0 += 32){
    *(ushort8*)(&As[arow*LDSK + akb]) = ldA(Ab, agr, k0 + akb);
    {
      ushort8 t8 = ldA(Bb, bgc, k0 + bkb);
      if (NEGB && bgc < HP){
        ushort one = f2bf(1.0f);
        if (bgc == 0 || bgc == HP-1){
          #pragma unroll
          for (int i=0;i<8;i++){ int kk = k0+bkb+i; if (kk < HP) t8[i] = one; }
        } else {
          #pragma unroll
          for (int i=0;i<8;i++){
            int kk = k0+bkb+i;
            if (kk < HP) t8[i] = (kk==0 || kk==HP-1) ? one : (ushort)(t8[i] ^ 0x8000);
          }
        }
      }
      *(ushort8*)(&Bs[bn*LDSK + bkb]) = t8;
    }
    MM_MFMA_STEP();
  }
  double local = 0.0;
  auto addq = [&](f32x4 v, int r0, int c0){
    if (c0 < HP){
      #pragma unroll
      for (int r=0;r<4;r++){
        int rr = r0 + r;
        if (rr < HP){
          float o = Ob[(size_t)rr*HP + c0];
          if (NEGB) o = (rr==0||rr==HP-1||c0==0||c0==HP-1) ? 1.0f : -o;
          local += (double)fabsf(o - v[r]);
        }
      }
    }
  };
  addq(acc00, rowBase + wr +      lq*4, colBase + wc +      l15);
  addq(acc01, rowBase + wr +      lq*4, colBase + wc + 16 + l15);
  addq(acc10, rowBase + wr + 16 + lq*4, colBase + wc +      l15);
  addq(acc11, rowBase + wr + 16 + lq*4, colBase + wc + 16 + l15);
  red[tid] = local;
  __syncthreads();
  for (int s=128; s>0; s>>=1){ if (tid<s) red[tid]+=red[tid+s]; __syncthreads(); }
  if (tid==0) part[(size_t)blockIdx.z*25 + blockIdx.y*5 + blockIdx.x] = red[0];
}

// ------- per-pixel inv-norm over 30 ch (x2 dup); write scaled bf16 A --------
__global__ void invnorm_scale_k(const float* __restrict__ oper, ushort* __restrict__ An){
  int p = blockIdx.x*256 + threadIdx.x;
  if (p >= NPIX) return;
  int h = p / HP, w = p % HP;
  size_t pb = (size_t)h*BSTR + w;
  float v[C30];
  float ss = 0.0f;
  #pragma unroll
  for (int c=0;c<C30;c++){ v[c] = oper[(size_t)c*NPIX+p]; ss = fmaf(v[c],v[c],ss); }
  float n = sqrtf(2.0f*ss);
  float inv = 1.0f / fmaxf(n, 1e-12f);
  #pragma unroll
  for (int c=0;c<C30;c++) An[(size_t)c*NPB+pb] = f2bf(v[c]*inv);
}

// ---------------- column-sum partials of (y - x) over row chunks ------------
__global__ void colmean_part_k(const float* __restrict__ y, const float* __restrict__ x,
                               float* __restrict__ cmpart){
  int c = blockIdx.z, chunk = blockIdx.y;
  int w = blockIdx.x*256 + threadIdx.x;
  if (w >= HP) return;
  const float* yb = y + (size_t)c*NPIX;
  const float* xb = x + (size_t)c*NPIX;
  int r0 = chunk*33, r1 = min(HP, r0+33);
  float sum = 0.0f;
  for (int h=r0; h<r1; h++) sum += yb[h*HP+w] - xb[h*HP+w];
  cmpart[((size_t)chunk*C30 + c)*HP + w] = sum;
}

__global__ void combine_cm_k(const float* __restrict__ cmpart, float* __restrict__ cm){
  int idx = blockIdx.x*256 + threadIdx.x;
  if (idx >= C30*HP) return;
  float s = 0.0f;
  #pragma unroll
  for (int k=0;k<8;k++) s += cmpart[(size_t)k*C30*HP + idx];
  cm[idx] = s / (float)HP;
}

// ---------------- rectification: out = x + relu((y-x) - colmean) ------------
__global__ void rectify_k(const float* __restrict__ x, const float* __restrict__ y,
                          const float* __restrict__ cm, float* __restrict__ out){
  int idx = blockIdx.x*256 + threadIdx.x;
  if (idx >= TOT) return;
  int c = idx / NPIX, p = idx % NPIX;
  int w = p % HP;
  float xv = x[idx];
  float off = y[idx] - xv - cm[c*HP + w];
  out[idx] = xv + fmaxf(off, 0.0f);
}

// ------- fused rectify + inv-norm + scaled bf16 A write ---------------------
__global__ void rectify_invnorm_scale_k(const float* __restrict__ x, const float* __restrict__ y,
                                        const float* __restrict__ cm, ushort* __restrict__ An){
  int p = blockIdx.x*256 + threadIdx.x;
  if (p >= NPIX) return;
  int h = p / HP, w = p % HP;
  size_t pb = (size_t)h*BSTR + w;
  float v[C30];
  float ss = 0.0f;
  #pragma unroll
  for (int c=0;c<C30;c++){
    float xv = x[(size_t)c*NPIX + p];
    float off = y[(size_t)c*NPIX + p] - xv - cm[c*HP + w];
    float vv = xv + fmaxf(off, 0.0f);
    v[c] = vv;
    ss = fmaf(vv, vv, ss);
  }
  float n = sqrtf(2.0f*ss);
  float inv = 1.0f / fmaxf(n, 1e-12f);
  #pragma unroll
  for (int c=0;c<C30;c++) An[(size_t)c*NPB+pb] = f2bf(v[c]*inv);
}

// ---------------- final: |2*(S0 - S1)| + base_loss --------------------------
__global__ void finalize_k(const double* __restrict__ part,
                           const float* __restrict__ base, float* __restrict__ out){
  __shared__ double s0[256], s1[256];
  int tid = threadIdx.x;
  double l0=0.0, l1=0.0;
  for (int i=tid;i<750;i+=256){ l0 += part[i]; l1 += part[750+i]; }
  s0[tid]=l0; s1[tid]=l1; __syncthreads();
  for (int s=128;s>0;s>>=1){ if (tid<s){ s0[tid]+=s0[tid+s]; s1[tid]+=s1[tid+s]; } __syncthreads(); }
  if (tid==0){
    out[0] = (float)(fabs(2.0*(s0[0]-s1[0])) + (double)base[0]);
  }
}

extern "C" void kernel_launch(void* const* d_in, const int* in_sizes, int n_in,
                              void* d_out, int out_size, void* d_ws, size_t ws_size,
                              hipStream_t stream){
  const float* logits = (const float*)d_in[0];
  const float* base   = (const float*)d_in[1];
  float* out = (float*)d_out;

  char* ws = (char*)d_ws;
  size_t off = 0;
  auto alloc = [&](size_t bytes)->char*{
    char* p = ws + off; off = (off + bytes + 255) & ~(size_t)255; return p;
  };
  double* part   = (double*)alloc(1500*sizeof(double));
  float*  cm     = (float*) alloc((size_t)C30*HP*sizeof(float));
  float*  cmpart = (float*) alloc((size_t)8*C30*HP*sizeof(float));
  float*  XP     = (float*) alloc((size_t)TOT*sizeof(float));
  ushort* XPbf   = (ushort*)alloc((size_t)C30*NPB*sizeof(ushort));
  ushort* XPbfT  = (ushort*)alloc((size_t)C30*NPB*sizeof(ushort));
  ushort* BF_A   = (ushort*)alloc((size_t)C30*NPB*sizeof(ushort));
  ushort* BF_B   = (ushort*)alloc((size_t)C30*NPB*sizeof(ushort));
  ushort* BF_C   = (ushort*)alloc((size_t)C30*NPB*sizeof(ushort));
  float*  F1     = (float*) alloc((size_t)TOT*sizeof(float));
  float*  F2     = (float*) alloc((size_t)TOT*sizeof(float));
  float*  X1     = (float*) alloc((size_t)TOT*sizeof(float));
  (void)ws_size; (void)in_sizes; (void)n_in; (void)out_size;

  dim3 mmGrid((HP+63)/64, (HP+63)/64, C30);          // 5 x 5 x 30
  dim3 trGrid((HP+31)/32, (HP+31)/32, C30);          // 9 x 9 x 30
  dim3 cmGrid((HP+255)/256, 8, C30);
  dim3 poolGrid((NPIX+255)/256, C30);
  int eb = (NPIX+255)/256;
  int tb = (TOT+255)/256;
  int cb = (C30*HP+255)/256;

  build_fc_k<<<eb,256,0,stream>>>(logits, XP, XPbf);
  transpose_k<<<trGrid,dim3(32,8),0,stream>>>(XPbf, XPbfT);
  pool_both_k<<<poolGrid,256,0,stream>>>(XP, BF_A, BF_B);   // max -> BF_A, avg -> BF_B

  // ---- opening ----
  mm_store_k<<<mmGrid,256,0,stream>>>(BF_A, XPbfT, F1);            // C1
  pool_one_k<1><<<poolGrid,256,0,stream>>>(F1, BF_C);
  mm_store_k<<<mmGrid,256,0,stream>>>(BF_C, XPbfT, F2);            // operated_open
  invnorm_scale_k<<<eb,256,0,stream>>>(F2, BF_A);                  // An
  mm_absred_k<1><<<mmGrid,256,0,stream>>>(BF_A, XPbfT, XP, part);

  // ---- dilation ----
  mm_store_k<<<mmGrid,256,0,stream>>>(BF_B, XPbfT, F1);            // y1
  colmean_part_k<<<cmGrid,256,0,stream>>>(F1, XP, cmpart);
  combine_cm_k<<<cb,256,0,stream>>>(cmpart, cm);
  rectify_k<<<tb,256,0,stream>>>(XP, F1, cm, X1);                  // x1
  pool_one_k<0><<<poolGrid,256,0,stream>>>(X1, BF_C);
  mm_store_k<<<mmGrid,256,0,stream>>>(BF_C, XPbfT, F2);            // y2
  colmean_part_k<<<cmGrid,256,0,stream>>>(F2, X1, cmpart);
  combine_cm_k<<<cb,256,0,stream>>>(cmpart, cm);
  rectify_invnorm_scale_k<<<eb,256,0,stream>>>(X1, F2, cm, BF_A);  // An2
  mm_absred_k<0><<<mmGrid,256,0,stream>>>(BF_A, XPbfT, XP, part + 750);

  finalize_k<<<1,256,0,stream>>>(part, base, out);
}

// Round 6
// 184.361 us; speedup vs baseline: 1.7343x; 1.0003x over previous
//
#include <hip/hip_runtime.h>
#include <math.h>

#define HP 258
#define RPAD 320              // padded rows for bf16 operand buffers
#define BSTR 328              // bf16 row stride (656B; dword stride 164 %32=4 -> period-8 banks)
#define NPIX (HP*HP)          // 66564
#define NPB  (RPAD*BSTR)      // 104960 bf16 elems per channel
#define PTOT (RPAD*BSTR)      // padded per-channel pixel count
#define C30 30
#define TOT (C30*NPIX)
#define LOGW 64

typedef __bf16 bf16x8 __attribute__((ext_vector_type(8)));
typedef float  f32x4  __attribute__((ext_vector_type(4)));
typedef unsigned short ushort;
typedef unsigned short ushort8 __attribute__((ext_vector_type(8)));

static __device__ inline ushort f2bf(float f){
  __bf16 h = (__bf16)f;
  return __builtin_bit_cast(ushort, h);
}

// ---------------- build padded fc channels (30 distinct, each x2 in ref) ----
__global__ void build_fc_k(const float* __restrict__ logits,
                           float* __restrict__ xp, ushort* __restrict__ xpbf){
  int p = blockIdx.x*256 + threadIdx.x;
  if (p >= PTOT) return;
  int h = p / BSTR, w = p % BSTR;
  if (h >= HP || w >= HP){                      // zero pad region
    #pragma unroll
    for (int c=0;c<C30;c++) xpbf[(size_t)c*NPB+p] = 0;
    return;
  }
  int pd = h*HP + w;                            // dense fp32 index
  if (h==0 || h==HP-1 || w==0 || w==HP-1){
    ushort one = f2bf(1.0f);
    #pragma unroll
    for (int c=0;c<C30;c++){ xp[(size_t)c*NPIX+pd] = 1.0f; xpbf[(size_t)c*NPB+p] = one; }
    return;
  }
  int oh = h-1, ow = w-1;
  float fy = 0.25f*oh - 0.375f;
  float fx = 0.25f*ow - 0.375f;
  float y0f = floorf(fy), x0f = floorf(fx);
  float ty = fy - y0f, tx = fx - x0f;
  int y0 = max(0, (int)y0f), y1 = min(LOGW-1, (int)y0f + 1);
  int x0 = max(0, (int)x0f), x1 = min(LOGW-1, (int)x0f + 1);
  float s[6];
  float m = -3.402823466e+38f;
  #pragma unroll
  for (int c=0;c<6;c++){
    const float* pl = logits + c*LOGW*LOGW;
    float v00 = pl[y0*LOGW + x0], v01 = pl[y0*LOGW + x1];
    float v10 = pl[y1*LOGW + x0], v11 = pl[y1*LOGW + x1];
    float a = v00 + (v01 - v00)*tx;
    float b = v10 + (v11 - v10)*tx;
    float v = a + (b - a)*ty;
    s[c] = v; m = fmaxf(m, v);
  }
  float sum = 0.0f;
  #pragma unroll
  for (int c=0;c<6;c++){ s[c] = expf(s[c]-m); sum += s[c]; }
  float inv = 1.0f/sum;
  #pragma unroll
  for (int c=0;c<6;c++) s[c] *= inv;
  #pragma unroll
  for (int c=0;c<C30;c++){
    int i = c/5, r = c%5;
    int j = r + (r>=i ? 1 : 0);
    float d = 0.5f*(s[i]-s[j]);
    float v = fmaxf(d, 0.0f);
    xp[(size_t)c*NPIX+pd]  = v;
    xpbf[(size_t)c*NPB+p] = f2bf(v);
  }
}

// ------- transpose padded bf16: dst[i][j] = src[j][i], i,j in [0,RPAD) ------
// grid: x covers j0 (src row / dst col) 0..288, y covers i0 (src col / dst
// row) 0..288 -> i,j <= 319 < RPAD: all reads/writes stay inside the channel.
// dst cols 320..327 are never written and never read by the matmuls (k<=287).
__global__ void transpose_k(const ushort* __restrict__ src, ushort* __restrict__ dst){
  __shared__ ushort t[32][33];
  int ch = blockIdx.z;
  const ushort* s = src + (size_t)ch*NPB;
  ushort*       d = dst + (size_t)ch*NPB;
  int j0 = blockIdx.x*32;          // src row / dst col
  int i0 = blockIdx.y*32;          // src col / dst row
  #pragma unroll
  for (int k=0;k<4;k++){
    int jj = threadIdx.y + k*8, ii = threadIdx.x;
    int j = j0 + jj, i = i0 + ii;
    t[jj][ii] = s[(size_t)j*BSTR + i];
  }
  __syncthreads();
  #pragma unroll
  for (int k=0;k<4;k++){
    int ii = threadIdx.y + k*8, jj = threadIdx.x;
    int i = i0 + ii, j = j0 + jj;
    d[(size_t)i*BSTR + j] = t[jj][ii];
  }
}

// ------------- combined max+avg 3x3 pool + pad, fp32 in -> padded bf16 ------
__global__ void pool_both_k(const float* __restrict__ X,
                            ushort* __restrict__ pmax, ushort* __restrict__ pavg){
  int c = blockIdx.y;
  int p = blockIdx.x*256 + threadIdx.x;
  if (p >= PTOT) return;
  int h = p / BSTR, w = p % BSTR;
  size_t ob = (size_t)c*NPB + p;
  if (h >= HP || w >= HP){ pmax[ob] = 0; pavg[ob] = 0; return; }
  if (h==0 || h==HP-1 || w==0 || w==HP-1){
    ushort one = f2bf(1.0f);
    pmax[ob] = one; pavg[ob] = one;
    return;
  }
  const float* s = X + (size_t)c*NPIX;
  float mv = -3.402823466e+38f, av = 0.0f;
  #pragma unroll
  for (int dy=-1;dy<=1;dy++){
    const float* r = s + (size_t)(h+dy)*HP + (w-1);
    float a = r[0], b = r[1], d = r[2];
    mv = fmaxf(mv, fmaxf(fmaxf(a,b),d));
    av += a+b+d;
  }
  pmax[ob] = f2bf(mv);
  pavg[ob] = f2bf(av*(1.0f/9.0f));
}

// ---------------- single 3x3 pool + pad, fp32 in -> padded bf16 -------------
template<int MAXP>
__global__ void pool_one_k(const float* __restrict__ X, ushort* __restrict__ out){
  int c = blockIdx.y;
  int p = blockIdx.x*256 + threadIdx.x;
  if (p >= PTOT) return;
  int h = p / BSTR, w = p % BSTR;
  size_t ob = (size_t)c*NPB + p;
  if (h >= HP || w >= HP){ out[ob] = 0; return; }
  if (h==0 || h==HP-1 || w==0 || w==HP-1){ out[ob] = f2bf(1.0f); return; }
  const float* s = X + (size_t)c*NPIX;
  if (MAXP){
    float mv = -3.402823466e+38f;
    #pragma unroll
    for (int dy=-1;dy<=1;dy++){
      const float* r = s + (size_t)(h+dy)*HP + (w-1);
      mv = fmaxf(mv, fmaxf(fmaxf(r[0],r[1]),r[2]));
    }
    out[ob] = f2bf(mv);
  } else {
    float av = 0.0f;
    #pragma unroll
    for (int dy=-1;dy<=1;dy++){
      const float* r = s + (size_t)(h+dy)*HP + (w-1);
      av += r[0]+r[1]+r[2];
    }
    out[ob] = f2bf(av*(1.0f/9.0f));
  }
}

// ---------------- MFMA matmul core (branch-free staging, BK=64 + 32 tail) ---
#define MM_PROLOGUE()                                                          \
  int tid = threadIdx.x;                                                       \
  int lane = tid & 63, wv = tid >> 6;                                          \
  int wr = (wv >> 1)*32, wc = (wv & 1)*32;                                     \
  int rowBase = blockIdx.x*64, colBase = blockIdx.y*64;                        \
  int l15 = lane & 15, lq = lane >> 4;                                         \
  f32x4 acc00 = {0.f,0.f,0.f,0.f}, acc01 = acc00, acc10 = acc00, acc11 = acc00;\
  int srow = tid >> 3, sc8 = tid & 7;   /* staging: rows srow, srow+32 */

#define MM_MFMA_HALF(KK)                                                       \
  {                                                                            \
    bf16x8 a0 = __builtin_bit_cast(bf16x8, *(const ushort8*)(&As[(wr      + l15)*72 + (KK) + lq*8])); \
    bf16x8 a1 = __builtin_bit_cast(bf16x8, *(const ushort8*)(&As[(wr + 16 + l15)*72 + (KK) + lq*8])); \
    bf16x8 b0 = __builtin_bit_cast(bf16x8, *(const ushort8*)(&Bs[(wc      + l15)*72 + (KK) + lq*8])); \
    bf16x8 b1 = __builtin_bit_cast(bf16x8, *(const ushort8*)(&Bs[(wc + 16 + l15)*72 + (KK) + lq*8])); \
    acc00 = __builtin_amdgcn_mfma_f32_16x16x32_bf16(a0, b0, acc00, 0, 0, 0);   \
    acc01 = __builtin_amdgcn_mfma_f32_16x16x32_bf16(a0, b1, acc01, 0, 0, 0);   \
    acc10 = __builtin_amdgcn_mfma_f32_16x16x32_bf16(a1, b0, acc10, 0, 0, 0);   \
    acc11 = __builtin_amdgcn_mfma_f32_16x16x32_bf16(a1, b1, acc11, 0, 0, 0);   \
  }

// ---------------- mm_store: C(fp32 dense) = A(bf16 pad) @ B(bf16 pad T) -----
__global__ __launch_bounds__(256) void mm_store_k(const ushort* __restrict__ A,
                                                  const ushort* __restrict__ BT,
                                                  float* __restrict__ C){
  __shared__ ushort As[64*72];
  __shared__ ushort Bs[64*72];
  int ch = blockIdx.z;
  MM_PROLOGUE();
  const ushort* Ab = A  + (size_t)ch*NPB + (size_t)rowBase*BSTR;
  const ushort* Bb = BT + (size_t)ch*NPB + (size_t)colBase*BSTR;
  const ushort* apt = Ab + (size_t)srow*BSTR + sc8*8;
  const ushort* bpt = Bb + (size_t)srow*BSTR + sc8*8;
  float*        Cb = C  + (size_t)ch*NPIX;
  for (int k0 = 0; k0 < 256; k0 += 64){
    *(ushort8*)(&As[srow*72 + sc8*8])      = *(const ushort8*)(apt + k0);
    *(ushort8*)(&As[(srow+32)*72 + sc8*8]) = *(const ushort8*)(apt + (size_t)32*BSTR + k0);
    *(ushort8*)(&Bs[srow*72 + sc8*8])      = *(const ushort8*)(bpt + k0);
    *(ushort8*)(&Bs[(srow+32)*72 + sc8*8]) = *(const ushort8*)(bpt + (size_t)32*BSTR + k0);
    __syncthreads();
    MM_MFMA_HALF(0);
    MM_MFMA_HALF(32);
    __syncthreads();
  }
  {  // tail: k = 256..287 (cols 258..287 are zero pad)
    int row4 = tid >> 2, c84 = tid & 3;
    *(ushort8*)(&As[row4*72 + c84*8]) = *(const ushort8*)(Ab + (size_t)row4*BSTR + 256 + c84*8);
    *(ushort8*)(&Bs[row4*72 + c84*8]) = *(const ushort8*)(Bb + (size_t)row4*BSTR + 256 + c84*8);
    __syncthreads();
    MM_MFMA_HALF(0);
  }
  auto store = [&](f32x4 v, int r0, int c0){
    if (c0 < HP){
      #pragma unroll
      for (int r=0;r<4;r++){
        int rr = r0 + r;
        if (rr < HP) Cb[(size_t)rr*HP + c0] = v[r];
      }
    }
  };
  store(acc00, rowBase + wr +      lq*4, colBase + wc +      l15);
  store(acc01, rowBase + wr +      lq*4, colBase + wc + 16 + l15);
  store(acc10, rowBase + wr + 16 + lq*4, colBase + wc +      l15);
  store(acc11, rowBase + wr + 16 + lq*4, colBase + wc + 16 + l15);
}

// ------- mm_absred: acc = A @ (±B); part += |operand - acc| (no C write) ----
template<int NEGB>
__global__ __launch_bounds__(256) void mm_absred_k(const ushort* __restrict__ A,
                                                   const ushort* __restrict__ BT,
                                                   const float* __restrict__ XPop,
                                                   double* __restrict__ part){
  __shared__ ushort As[64*72];
  __shared__ ushort Bs[64*72];
  __shared__ double red[256];
  int ch = blockIdx.z;
  MM_PROLOGUE();
  const ushort* Ab = A  + (size_t)ch*NPB + (size_t)rowBase*BSTR;
  const ushort* Bb = BT + (size_t)ch*NPB + (size_t)colBase*BSTR;
  const ushort* apt = Ab + (size_t)srow*BSTR + sc8*8;
  const ushort* bpt = Bb + (size_t)srow*BSTR + sc8*8;
  const float*  Ob = XPop + (size_t)ch*NPIX;
  ushort one = f2bf(1.0f);
  auto fixB = [&](ushort8 t8, int brow, int kbase)->ushort8{
    if (!NEGB) return t8;
    if (brow >= HP) return t8;                  // zero pad rows stay zero
    #pragma unroll
    for (int i=0;i<8;i++){
      int kk = kbase + i;
      if (kk < HP)
        t8[i] = (brow==0 || brow==HP-1 || kk==0 || kk==HP-1) ? one : (ushort)(t8[i] ^ 0x8000);
      // kk >= HP: keep staged zero
    }
    return t8;
  };
  for (int k0 = 0; k0 < 256; k0 += 64){
    *(ushort8*)(&As[srow*72 + sc8*8])      = *(const ushort8*)(apt + k0);
    *(ushort8*)(&As[(srow+32)*72 + sc8*8]) = *(const ushort8*)(apt + (size_t)32*BSTR + k0);
    *(ushort8*)(&Bs[srow*72 + sc8*8])      = fixB(*(const ushort8*)(bpt + k0), colBase + srow, k0 + sc8*8);
    *(ushort8*)(&Bs[(srow+32)*72 + sc8*8]) = fixB(*(const ushort8*)(bpt + (size_t)32*BSTR + k0), colBase + srow + 32, k0 + sc8*8);
    __syncthreads();
    MM_MFMA_HALF(0);
    MM_MFMA_HALF(32);
    __syncthreads();
  }
  {
    int row4 = tid >> 2, c84 = tid & 3;
    *(ushort8*)(&As[row4*72 + c84*8]) = *(const ushort8*)(Ab + (size_t)row4*BSTR + 256 + c84*8);
    *(ushort8*)(&Bs[row4*72 + c84*8]) = fixB(*(const ushort8*)(Bb + (size_t)row4*BSTR + 256 + c84*8), colBase + row4, 256 + c84*8);
    __syncthreads();
    MM_MFMA_HALF(0);
  }
  double local = 0.0;
  auto addq = [&](f32x4 v, int r0, int c0){
    if (c0 < HP){
      #pragma unroll
      for (int r=0;r<4;r++){
        int rr = r0 + r;
        if (rr < HP){
          float o = Ob[(size_t)rr*HP + c0];
          if (NEGB) o = (rr==0||rr==HP-1||c0==0||c0==HP-1) ? 1.0f : -o;
          local += (double)fabsf(o - v[r]);
        }
      }
    }
  };
  addq(acc00, rowBase + wr +      lq*4, colBase + wc +      l15);
  addq(acc01, rowBase + wr +      lq*4, colBase + wc + 16 + l15);
  addq(acc10, rowBase + wr + 16 + lq*4, colBase + wc +      l15);
  addq(acc11, rowBase + wr + 16 + lq*4, colBase + wc + 16 + l15);
  red[tid] = local;
  __syncthreads();
  for (int s=128; s>0; s>>=1){ if (tid<s) red[tid]+=red[tid+s]; __syncthreads(); }
  if (tid==0) part[(size_t)blockIdx.z*25 + blockIdx.y*5 + blockIdx.x] = red[0];
}

// ------- per-pixel inv-norm over 30 ch (x2 dup); write scaled padded bf16 ---
__global__ void invnorm_scale_k(const float* __restrict__ oper, ushort* __restrict__ An){
  int p = blockIdx.x*256 + threadIdx.x;
  if (p >= PTOT) return;
  int h = p / BSTR, w = p % BSTR;
  if (h >= HP || w >= HP){
    #pragma unroll
    for (int c=0;c<C30;c++) An[(size_t)c*NPB+p] = 0;
    return;
  }
  int pd = h*HP + w;
  float v[C30];
  float ss = 0.0f;
  #pragma unroll
  for (int c=0;c<C30;c++){ v[c] = oper[(size_t)c*NPIX+pd]; ss = fmaf(v[c],v[c],ss); }
  float n = sqrtf(2.0f*ss);
  float inv = 1.0f / fmaxf(n, 1e-12f);
  #pragma unroll
  for (int c=0;c<C30;c++) An[(size_t)c*NPB+p] = f2bf(v[c]*inv);
}

// ---------------- column-sum partials of (y - x) over row chunks ------------
__global__ void colmean_part_k(const float* __restrict__ y, const float* __restrict__ x,
                               float* __restrict__ cmpart){
  int c = blockIdx.z, chunk = blockIdx.y;
  int w = blockIdx.x*256 + threadIdx.x;
  if (w >= HP) return;
  const float* yb = y + (size_t)c*NPIX;
  const float* xb = x + (size_t)c*NPIX;
  int r0 = chunk*33, r1 = min(HP, r0+33);
  float sum = 0.0f;
  for (int h=r0; h<r1; h++) sum += yb[h*HP+w] - xb[h*HP+w];
  cmpart[((size_t)chunk*C30 + c)*HP + w] = sum;
}

__global__ void combine_cm_k(const float* __restrict__ cmpart, float* __restrict__ cm){
  int idx = blockIdx.x*256 + threadIdx.x;
  if (idx >= C30*HP) return;
  float s = 0.0f;
  #pragma unroll
  for (int k=0;k<8;k++) s += cmpart[(size_t)k*C30*HP + idx];
  cm[idx] = s / (float)HP;
}

// ---------------- rectification: out = x + relu((y-x) - colmean) ------------
__global__ void rectify_k(const float* __restrict__ x, const float* __restrict__ y,
                          const float* __restrict__ cm, float* __restrict__ out){
  int idx = blockIdx.x*256 + threadIdx.x;
  if (idx >= TOT) return;
  int c = idx / NPIX, p = idx % NPIX;
  int w = p % HP;
  float xv = x[idx];
  float off = y[idx] - xv - cm[c*HP + w];
  out[idx] = xv + fmaxf(off, 0.0f);
}

// ------- fused rectify + inv-norm + scaled padded bf16 A write --------------
__global__ void rectify_invnorm_scale_k(const float* __restrict__ x, const float* __restrict__ y,
                                        const float* __restrict__ cm, ushort* __restrict__ An){
  int p = blockIdx.x*256 + threadIdx.x;
  if (p >= PTOT) return;
  int h = p / BSTR, w = p % BSTR;
  if (h >= HP || w >= HP){
    #pragma unroll
    for (int c=0;c<C30;c++) An[(size_t)c*NPB+p] = 0;
    return;
  }
  int pd = h*HP + w;
  float v[C30];
  float ss = 0.0f;
  #pragma unroll
  for (int c=0;c<C30;c++){
    float xv = x[(size_t)c*NPIX + pd];
    float off = y[(size_t)c*NPIX + pd] - xv - cm[c*HP + w];
    float vv = xv + fmaxf(off, 0.0f);
    v[c] = vv;
    ss = fmaf(vv, vv, ss);
  }
  float n = sqrtf(2.0f*ss);
  float inv = 1.0f / fmaxf(n, 1e-12f);
  #pragma unroll
  for (int c=0;c<C30;c++) An[(size_t)c*NPB+p] = f2bf(v[c]*inv);
}

// ---------------- final: |2*(S0 - S1)| + base_loss --------------------------
__global__ void finalize_k(const double* __restrict__ part,
                           const float* __restrict__ base, float* __restrict__ out){
  __shared__ double s0[256], s1[256];
  int tid = threadIdx.x;
  double l0=0.0, l1=0.0;
  for (int i=tid;i<750;i+=256){ l0 += part[i]; l1 += part[750+i]; }
  s0[tid]=l0; s1[tid]=l1; __syncthreads();
  for (int s=128;s>0;s>>=1){ if (tid<s){ s0[tid]+=s0[tid+s]; s1[tid]+=s1[tid+s]; } __syncthreads(); }
  if (tid==0){
    out[0] = (float)(fabs(2.0*(s0[0]-s1[0])) + (double)base[0]);
  }
}

extern "C" void kernel_launch(void* const* d_in, const int* in_sizes, int n_in,
                              void* d_out, int out_size, void* d_ws, size_t ws_size,
                              hipStream_t stream){
  const float* logits = (const float*)d_in[0];
  const float* base   = (const float*)d_in[1];
  float* out = (float*)d_out;

  char* ws = (char*)d_ws;
  size_t off = 0;
  auto alloc = [&](size_t bytes)->char*{
    char* p = ws + off; off = (off + bytes + 255) & ~(size_t)255; return p;
  };
  double* part   = (double*)alloc(1500*sizeof(double));
  float*  cm     = (float*) alloc((size_t)C30*HP*sizeof(float));
  float*  cmpart = (float*) alloc((size_t)8*C30*HP*sizeof(float));
  float*  XP     = (float*) alloc((size_t)TOT*sizeof(float));
  ushort* BF0    = (ushort*)alloc((size_t)C30*NPB*sizeof(ushort));  // XPbf -> pooled scratch
  ushort* BFT    = (ushort*)alloc((size_t)C30*NPB*sizeof(ushort));  // XP transposed
  ushort* BF1    = (ushort*)alloc((size_t)C30*NPB*sizeof(ushort));  // max pool -> An
  ushort* BF2    = (ushort*)alloc((size_t)C30*NPB*sizeof(ushort));  // avg pool -> x1 pooled
  float*  F1     = (float*) alloc((size_t)TOT*sizeof(float));
  float*  X1     = (float*) alloc((size_t)TOT*sizeof(float));
  (void)ws_size; (void)in_sizes; (void)n_in; (void)out_size;

  dim3 mmGrid((HP+63)/64, (HP+63)/64, C30);          // 5 x 5 x 30
  dim3 trGrid(RPAD/32, RPAD/32, C30);                // 10 x 10 x 30 — i,j <= 319
  dim3 cmGrid((HP+255)/256, 8, C30);
  dim3 padGrid((PTOT+255)/256, C30);
  int pb = (PTOT+255)/256;
  int tb = (TOT+255)/256;
  int cb = (C30*HP+255)/256;

  build_fc_k<<<pb,256,0,stream>>>(logits, XP, BF0);
  transpose_k<<<trGrid,dim3(32,8),0,stream>>>(BF0, BFT);
  pool_both_k<<<padGrid,256,0,stream>>>(XP, BF1, BF2);   // max -> BF1, avg -> BF2

  // ---- opening ----
  mm_store_k<<<mmGrid,256,0,stream>>>(BF1, BFT, F1);             // C1
  pool_one_k<1><<<padGrid,256,0,stream>>>(F1, BF0);              // BF0 free after transpose
  mm_store_k<<<mmGrid,256,0,stream>>>(BF0, BFT, F1);             // operated_open
  invnorm_scale_k<<<pb,256,0,stream>>>(F1, BF1);                 // An (BF1 free)
  mm_absred_k<1><<<mmGrid,256,0,stream>>>(BF1, BFT, XP, part);

  // ---- dilation ----
  mm_store_k<<<mmGrid,256,0,stream>>>(BF2, BFT, F1);             // y1
  colmean_part_k<<<cmGrid,256,0,stream>>>(F1, XP, cmpart);
  combine_cm_k<<<cb,256,0,stream>>>(cmpart, cm);
  rectify_k<<<tb,256,0,stream>>>(XP, F1, cm, X1);                // x1
  pool_one_k<0><<<padGrid,256,0,stream>>>(X1, BF2);              // BF2 free after y1
  mm_store_k<<<mmGrid,256,0,stream>>>(BF2, BFT, F1);             // y2 (y1 consumed)
  colmean_part_k<<<cmGrid,256,0,stream>>>(F1, X1, cmpart);
  combine_cm_k<<<cb,256,0,stream>>>(cmpart, cm);
  rectify_invnorm_scale_k<<<pb,256,0,stream>>>(X1, F1, cm, BF1); // An2
  mm_absred_k<0><<<mmGrid,256,0,stream>>>(BF1, BFT, XP, part + 750);

  finalize_k<<<1,256,0,stream>>>(part, base, out);
}